// Round 5
// baseline (16887.741 us; speedup 1.0000x reference)
//
#include <hip/hip_runtime.h>
#include <cstdint>
#include <cstddef>

#define NB 32
#define NT 64
#define NV 32000
#define NE 512
#define NH 1024
#define BOS_ID 1
#define EOS_ID 3

__device__ __forceinline__ unsigned mono_f32(float f) {
    unsigned u = __float_as_uint(f);
    return (u & 0x80000000u) ? ~u : (u | 0x80000000u);
}

// h0 = img @ Wp^T + bp ; c = 0
__global__ __launch_bounds__(256) void k_init(const float* __restrict__ img,
                                              const float* __restrict__ Wp,
                                              const float* __restrict__ bp,
                                              float* __restrict__ h0,
                                              float* __restrict__ c) {
    int g = blockIdx.x * 256 + threadIdx.x;   // 32768 outputs, one per thread
    int j = g >> 5, b = g & 31;
    const float* ir = img + (size_t)b * NH;   // D == 1024
    const float* wr = Wp + (size_t)j * NH;
    float s = bp[j];
    for (int k = 0; k < NH; k++) s = fmaf(ir[k], wr[k], s);
    h0[b * NH + j] = s;
    c[b * NH + j]  = 0.0f;
}

// logits + gumbel + argmax partial via device atomicMax.
// v6: k-halved GEMV for occupancy. 1000 blocks x 512 threads (8 waves).
//   Block owns 32 v; lane l -> v = blk*32 + (l&31), k-half h2 = l>>5 (512 k).
//   Wave w -> b in [4w, 4w+4); acc[4] per lane over its k-half; one
//   shfl_xor(32) + select gives both half-lanes the SAME half0+half1 order.
//   W chunk [32 v][2 half x 64 k] staged coalesced into 16 KB LDS, per-half
//   quad swizzle q' = q ^ (row&7): store and read both at the b128
//   8-lanes/bank-quad floor. h read per-t via immediate-offset global loads
//   (L1-resident; 8 waves/SIMD hide the latency -- that's the point of v6).
//   1000 blocks -> ~4 blocks/CU -> 32 waves/CU (vs v5's grid-capped 16).
//   Per-lane k-order strictly ascending within its half.
__global__ __launch_bounds__(512) void k_logit(const float* __restrict__ h,
                                               const float* __restrict__ Whv,
                                               const float* __restrict__ bhv,
                                               const float* __restrict__ gu,
                                               int s,
                                               unsigned long long* __restrict__ slot) {
    __shared__ __align__(16) float Wlds[32][128];   // 16 KB, quad-swizzled per half
    const int tid = threadIdx.x;
    const int l   = tid & 63;
    const int w   = tid >> 6;          // wave -> b-group [4w, 4w+4)
    const int lo  = l & 31;            // v offset within block
    const int h2  = l >> 5;            // k-half (0: k<512, 1: k>=512)
    const int v   = blockIdx.x * 32 + lo;
    const int lm  = lo & 7;            // read-side swizzle key

    // staging map: thread covers row r = tid>>4, half hs = (tid>>3)&1,
    // k-octet i8 = tid&7 (8 consecutive floats = 2 quads)
    const int r   = tid >> 4;          // 0..31
    const int hs  = (tid >> 3) & 1;
    const int i8  = tid & 7;
    const float* __restrict__ wsrc =
        Whv + (size_t)(blockIdx.x * 32 + r) * NH + hs * 512 + i8 * 8;
    float* const dst0 = &Wlds[r][hs * 64 + (((2 * i8 + 0) ^ (r & 7)) << 2)];
    float* const dst1 = &Wlds[r][hs * 64 + (((2 * i8 + 1) ^ (r & 7)) << 2)];

    const float* __restrict__ hb0 = h + (w * 4 + 0) * NH + h2 * 512;
    const float* __restrict__ hb1 = h + (w * 4 + 1) * NH + h2 * 512;
    const float* __restrict__ hb2 = h + (w * 4 + 2) * NH + h2 * 512;
    const float* __restrict__ hb3 = h + (w * 4 + 3) * NH + h2 * 512;

    float acc[4];
#pragma unroll
    for (int bi = 0; bi < 4; bi++) acc[bi] = 0.f;

    float4 st0 = *(const float4*)(wsrc + 0);   // chunk 0 -> regs (T14)
    float4 st1 = *(const float4*)(wsrc + 4);

    for (int c = 0; c < 8; c++) {              // 8 chunks x 64 k per half
        __syncthreads();                       // previous chunk's compute done
        *(float4*)dst0 = st0;                  // regs -> LDS (waits vmcnt)
        *(float4*)dst1 = st1;
        if (c < 7) {                           // issue next chunk's W loads early
            st0 = *(const float4*)(wsrc + (c + 1) * 64);
            st1 = *(const float4*)(wsrc + (c + 1) * 64 + 4);
        }
        __syncthreads();                       // LDS tile ready

        const int kc = c * 64;
        const float* __restrict__ p0 = hb0 + kc;
        const float* __restrict__ p1 = hb1 + kc;
        const float* __restrict__ p2 = hb2 + kc;
        const float* __restrict__ p3 = hb3 + kc;
#pragma unroll
        for (int t = 0; t < 16; t++) {
            const float4 w4 = *(const float4*)&Wlds[lo][h2 * 64 + ((t ^ lm) << 2)];
            const float4 ha = *(const float4*)&p0[4 * t];
            const float4 hb = *(const float4*)&p1[4 * t];
            const float4 hc = *(const float4*)&p2[4 * t];
            const float4 hd = *(const float4*)&p3[4 * t];
            acc[0] = fmaf(ha.x, w4.x, acc[0]); acc[0] = fmaf(ha.y, w4.y, acc[0]);
            acc[0] = fmaf(ha.z, w4.z, acc[0]); acc[0] = fmaf(ha.w, w4.w, acc[0]);
            acc[1] = fmaf(hb.x, w4.x, acc[1]); acc[1] = fmaf(hb.y, w4.y, acc[1]);
            acc[1] = fmaf(hb.z, w4.z, acc[1]); acc[1] = fmaf(hb.w, w4.w, acc[1]);
            acc[2] = fmaf(hc.x, w4.x, acc[2]); acc[2] = fmaf(hc.y, w4.y, acc[2]);
            acc[2] = fmaf(hc.z, w4.z, acc[2]); acc[2] = fmaf(hc.w, w4.w, acc[2]);
            acc[3] = fmaf(hd.x, w4.x, acc[3]); acc[3] = fmaf(hd.y, w4.y, acc[3]);
            acc[3] = fmaf(hd.z, w4.z, acc[3]); acc[3] = fmaf(hd.w, w4.w, acc[3]);
        }
    }

    // k-half reduce: both half-lanes compute the SAME (half0 + half1) order,
    // so duplicate lanes carry bit-identical full sums.
#pragma unroll
    for (int bi = 0; bi < 4; bi++) {
        float o = __shfl_xor(acc[bi], 32, 64);
        acc[bi] = (h2 == 0) ? (acc[bi] + o) : (o + acc[bi]);
    }

    // epilogue: lane owns (v, 4 b's); lanes l and l^32 duplicate the same v.
    const float bv = bhv[v];
    const size_t gubase = (size_t)s * NB * NV;
#pragma unroll
    for (int bi = 0; bi < 4; bi++) {
        const int b = w * 4 + bi;
        float u  = gu[gubase + (size_t)b * NV + v];
        float g  = -logf(-logf(u + 1e-10f) + 1e-10f);
        float sc = acc[bi] + bv + g;          // TAU == 1.0
        unsigned long long key =
            ((unsigned long long)mono_f32(sc) << 32) | (unsigned)(~(unsigned)v);
#pragma unroll
        for (int m = 1; m < 64; m <<= 1) {
            unsigned long long o =
                (unsigned long long)__shfl_xor((long long)key, m, 64);
            if (o > key) key = o;
        }
        if (l == 0) atomicMax(&slot[(s & 1) * 32 + b], key);
    }
}

// argmax-finalize (read slots) + LSTM cell slice (4 h-outputs per block)
// v2: T14 async-stage split -- issue next chunk's global loads into regs
// before computing the current chunk; write regs->LDS after the barrier.
__global__ __launch_bounds__(256) void k_lstm(const float* __restrict__ h,
                                              float* __restrict__ hn,
                                              float* __restrict__ cbuf,
                                              const float* __restrict__ emb,
                                              const float* __restrict__ Wih,
                                              const float* __restrict__ Whh,
                                              const float* __restrict__ bih,
                                              const float* __restrict__ bhh,
                                              unsigned long long* __restrict__ slot,
                                              int* __restrict__ hist,
                                              int s, int skip) {
    __shared__ float Wt[512][20];   // [k][slot], stride 20: aligned f4, conflict-free reads
    __shared__ float xh[32][517];   // [b][k], stride 517: 2-way max on reads
    __shared__ int labels[32];
    const int tid = threadIdx.x, blk = blockIdx.x;
    const int b8 = tid >> 3, ks = tid & 7;

    if (s < 0) {
        if (tid < 32) labels[tid] = BOS_ID;
    } else {
        if (tid < 32) labels[tid] = (int)(~(unsigned)slot[(s & 1) * 32 + tid]);
    }
    if (tid >= 32 && tid < 64)
        slot[((s + 1) & 1) * 32 + (tid - 32)] = 0ull;   // pre-zero next parity
    if (s >= 0 && blk == 0 && tid < 32) hist[s * 32 + tid] = labels[tid];
    if (skip) return;

    const int j0 = blk * 4;
    float acc[16];
#pragma unroll
    for (int r = 0; r < 16; r++) acc[r] = 0.f;

    float wreg[32];
    float xreg[64];
    auto issue = [&](int chunk) {
#pragma unroll
        for (int i = 0; i < 32; i++) {     // 16 gate rows x 512 k -> regs
            int idx = i * 256 + tid;
            int slot_i = idx >> 9, k = idx & 511;
            int gate = slot_i >> 2, jj = slot_i & 3;
            int row = gate * NH + j0 + jj;
            wreg[i] = (chunk == 0) ? Wih[(size_t)row * NE + k]
                                   : Whh[(size_t)row * NH + (chunk - 1) * 512 + k];
        }
#pragma unroll
        for (int i = 0; i < 64; i++) {     // x / h chunk -> regs
            int idx = i * 256 + tid;
            int b = idx >> 9, k = idx & 511;
            xreg[i] = (chunk == 0) ? emb[(size_t)labels[b] * NE + k]
                                   : h[b * NH + (chunk - 1) * 512 + k];
        }
    };

    __syncthreads();                       // labels visible to all threads
    issue(0);
    for (int chunk = 0; chunk < 3; chunk++) {
        __syncthreads();                   // prior compute on LDS done
#pragma unroll
        for (int i = 0; i < 32; i++) {
            int idx = i * 256 + tid;
            Wt[idx & 511][idx >> 9] = wreg[i];
        }
#pragma unroll
        for (int i = 0; i < 64; i++) {
            int idx = i * 256 + tid;
            xh[idx >> 9][idx & 511] = xreg[i];
        }
        if (chunk < 2) issue(chunk + 1);   // overlap next-chunk loads w/ compute
        __syncthreads();
#pragma unroll 4
        for (int i = 0; i < 64; i++) {
            int k = ks + 8 * i;
            float xv = xh[b8][k];
            const float4 w0 = *(const float4*)&Wt[k][0];
            const float4 w1 = *(const float4*)&Wt[k][4];
            const float4 w2 = *(const float4*)&Wt[k][8];
            const float4 w3 = *(const float4*)&Wt[k][12];
            acc[0]  = fmaf(xv, w0.x, acc[0]);  acc[1]  = fmaf(xv, w0.y, acc[1]);
            acc[2]  = fmaf(xv, w0.z, acc[2]);  acc[3]  = fmaf(xv, w0.w, acc[3]);
            acc[4]  = fmaf(xv, w1.x, acc[4]);  acc[5]  = fmaf(xv, w1.y, acc[5]);
            acc[6]  = fmaf(xv, w1.z, acc[6]);  acc[7]  = fmaf(xv, w1.w, acc[7]);
            acc[8]  = fmaf(xv, w2.x, acc[8]);  acc[9]  = fmaf(xv, w2.y, acc[9]);
            acc[10] = fmaf(xv, w2.z, acc[10]); acc[11] = fmaf(xv, w2.w, acc[11]);
            acc[12] = fmaf(xv, w3.x, acc[12]); acc[13] = fmaf(xv, w3.y, acc[13]);
            acc[14] = fmaf(xv, w3.z, acc[14]); acc[15] = fmaf(xv, w3.w, acc[15]);
        }
    }
#pragma unroll
    for (int m = 1; m < 8; m <<= 1)
#pragma unroll
        for (int r = 0; r < 16; r++) acc[r] += __shfl_xor(acc[r], m, 64);

    if (ks == 0) {
        int b = b8;
#pragma unroll
        for (int jj = 0; jj < 4; jj++) {
            int j = j0 + jj;
            float gi = acc[0 + jj]  + bih[j]          + bhh[j];
            float gf = acc[4 + jj]  + bih[NH + j]     + bhh[NH + j];
            float gg = acc[8 + jj]  + bih[2 * NH + j] + bhh[2 * NH + j];
            float go = acc[12 + jj] + bih[3 * NH + j] + bhh[3 * NH + j];
            float si = 1.f / (1.f + expf(-gi));
            float sf = 1.f / (1.f + expf(-gf));
            float so = 1.f / (1.f + expf(-go));
            float cn = sf * cbuf[b * NH + j] + si * tanhf(gg);
            float hv = so * tanhf(cn);
            cbuf[b * NH + j] = cn;
            hn[b * NH + j]   = hv;
        }
    }
}

// ids / lengths from label history
__global__ __launch_bounds__(64) void k_out(const int* __restrict__ hist,
                                            float* __restrict__ out) {
    int b = threadIdx.x;
    if (b >= 32) return;
    int te = 63;   // first EOS index (t=63 forced EOS)
    for (int t = 0; t < 63; t++)
        if (hist[t * 32 + b] == EOS_ID) { te = t; break; }
    for (int t = 0; t < 64; t++) {
        int lab = (t < 63) ? hist[t * 32 + b] : EOS_ID;
        int id = (t < te) ? lab : 0;           // pad_g true strictly before first EOS
        out[b * 64 + t] = (float)id;
    }
    out[2048 + (size_t)NB * NT * NV + b] = (float)(te + 1);
}

// zero logits region + scatter one-hot (message_logits == one_hot(message_ids))
__global__ __launch_bounds__(256) void k_scatter(float* __restrict__ out) {
    const int bt = blockIdx.x;                 // b*64 + t
    float* row = out + 2048 + (size_t)bt * NV;
    const int id = (int)out[bt];               // ids already written by k_out
    float4 z = make_float4(0.f, 0.f, 0.f, 0.f);
    for (int i = threadIdx.x; i < NV / 4; i += 256) ((float4*)row)[i] = z;
    __syncthreads();
    if (threadIdx.x == 0) row[id] = 1.0f;
}

extern "C" void kernel_launch(void* const* d_in, const int* in_sizes, int n_in,
                              void* d_out, int out_size, void* d_ws, size_t ws_size,
                              hipStream_t stream) {
    const float* img = (const float*)d_in[0];
    const float* gu  = (const float*)d_in[1];
    const float* Wp  = (const float*)d_in[2];
    const float* bp  = (const float*)d_in[3];
    const float* emb = (const float*)d_in[4];
    const float* Wih = (const float*)d_in[5];
    const float* Whh = (const float*)d_in[6];
    const float* bih = (const float*)d_in[7];
    const float* bhh = (const float*)d_in[8];
    const float* Whv = (const float*)d_in[9];
    const float* bhv = (const float*)d_in[10];
    float* out = (float*)d_out;

    // scratch lives inside the logits region of d_out (fully overwritten by k_scatter)
    float* scratch = out + 2048;
    float* hA = scratch;                 // 32768
    float* hB = scratch + 32768;         // 32768
    float* cb = scratch + 65536;         // 32768
    unsigned long long* slot = (unsigned long long*)(scratch + 98304); // 64 u64 (2 parities)
    int* hist = (int*)(scratch + 98304 + 128);                         // 63*32 ints

    k_init<<<128, 256, 0, stream>>>(img, Wp, bp, hB, cb);
    // initial LSTM cell with x0 = emb[BOS], h = h0, c = 0 -> writes hA; zeroes slot parity 0
    k_lstm<<<256, 256, 0, stream>>>(hB, hA, cb, emb, Wih, Whh, bih, bhh,
                                    slot, hist, -1, 0);
    for (int s = 0; s < 63; s++) {
        const float* hc = (s & 1) ? hB : hA;
        float* hn       = (s & 1) ? hA : hB;
        k_logit<<<1000, 512, 0, stream>>>(hc, Whv, bhv, gu, s, slot);
        k_lstm<<<256, 256, 0, stream>>>(hc, hn, cb, emb, Wih, Whh, bih, bhh,
                                        slot, hist, s, (s == 62) ? 1 : 0);
    }
    k_out<<<1, 64, 0, stream>>>(hist, out);
    k_scatter<<<2048, 256, 0, stream>>>(out);
}